// Round 2
// baseline (70.563 us; speedup 1.0000x reference)
//
#include <hip/hip_runtime.h>
#include <stdint.h>

// Problem constants (fixed by setup_inputs)
#define BB 64
#define TT 8192
#define VV 50257
// max_phrase_len = 32, pad_token_id = 0 (hardcoded)

// Workspace layout (byte offsets)
#define WS_FLAGS   0                       // int[4]: table dtype flag
#define WS_NFIRES  256                     // int[BB]
#define WS_NATW    4096                    // uint64[BB*128]
#define WS_REALW   (4096 + 65536)          // uint64[BB*128]
#define WS_FIRES   (4096 + 2 * 65536)      // int[BB*TT]

// ---------------------------------------------------------------------------
// Kernel D: detect how the bool tables (is_punct / is_abbreviation) were
// pushed: 0 = int32 (0/1), 1 = uint8 (1 byte per bool), 2 = float32.
// Probe the first 4096 int32 words (16 KB) -- in-bounds for all 3 layouts
// (uint8: 50257 B, int32: 201028 B, f32: 201028 B).
//   f32  : words contain bytes > 1 (1.0f = 0x3F800000)
//   uint8: bytes all in {0,1} but words > 1 (set bits above byte 0)
//   int32: all words in {0,1}
// ---------------------------------------------------------------------------
__global__ void detect_kernel(const void* __restrict__ punct, int* __restrict__ flags) {
    int lane = threadIdx.x;
    const uint32_t* w = (const uint32_t*)punct;
    bool byteGT1 = false, wordGT1 = false;
    for (int k = lane; k < 4096; k += 64) {
        uint32_t x = w[k];
        if ((x & 0xFEFEFEFEu) != 0u) byteGT1 = true;
        if (x > 1u)                  wordGT1 = true;
    }
    unsigned long long b1 = __ballot(byteGT1);
    unsigned long long b2 = __ballot(wordGT1);
    if (lane == 0) flags[0] = b1 ? 2 : (b2 ? 1 : 0);
}

__device__ __forceinline__ bool lut(const void* tbl, int flag, int idx) {
    if (flag == 2) return ((const float*)tbl)[idx]   != 0.0f;
    if (flag == 1) return ((const uint8_t*)tbl)[idx] != 0;
    return ((const int*)tbl)[idx] != 0;
}

// ---------------------------------------------------------------------------
// Kernel E: per-token natural-fire bit + real bit, packed into uint64 words
// via wave ballots.  natural[t] = real && ( (punct[id] && !(t>0 && abbr[prev]))
//                                           || t == last_real )
// t == last_real is local: real[t] && (t==T-1 || !real[t+1])  (real prefix).
// ---------------------------------------------------------------------------
__global__ void natural_kernel(const int* __restrict__ ids,
                               const void* __restrict__ punct,
                               const void* __restrict__ abbr,
                               const int* __restrict__ flags,
                               unsigned long long* __restrict__ natW,
                               unsigned long long* __restrict__ realW) {
    int g = blockIdx.x * blockDim.x + threadIdx.x;   // g = b*TT + t
    int t = g & (TT - 1);
    int flag = flags[0];
    int id = ids[g];
    bool real = (id != 0);
    bool isLR = real && ((t == TT - 1) || (ids[g + 1] == 0));
    bool e = false;
    if (real) {
        bool pu = lut(punct, flag, id);
        bool pa = (t > 0) ? lut(abbr, flag, ids[g - 1]) : false;
        e = pu && !pa;
    }
    bool natural = real && (e || isLR);
    unsigned long long nb = __ballot(natural);
    unsigned long long rb = __ballot(real);
    if ((threadIdx.x & 63) == 0) {
        int w = g >> 6;          // == b*128 + (t>>6)
        natW[w]  = nb;
        realW[w] = rb;
    }
}

// ---------------------------------------------------------------------------
// Kernel S: per-row fire scan, one wave per row.  Exact decomposition:
//   fire[t] = real[t] && ( natural[t] || ((t - prevNat(t)) & 31) == 0 )
// where prevNat(t) = last natural-fire position < t (or -1, matching the
// reference's last_boundary=-1 init: forced at t=31 since 31-(-1)=32).
// Emits fire positions (phrase end positions) to fires[], count to nfires[].
// ---------------------------------------------------------------------------
__device__ __forceinline__ unsigned long long shfl64(unsigned long long v, int src) {
    int lo = __shfl((int)(uint32_t)v, src);
    int hi = __shfl((int)(uint32_t)(v >> 32), src);
    return ((unsigned long long)(uint32_t)hi << 32) | (uint32_t)lo;
}

__global__ void scan_kernel(const unsigned long long* __restrict__ natW,
                            const unsigned long long* __restrict__ realW,
                            int* __restrict__ fires, int* __restrict__ nfires) {
    int b = blockIdx.x, lane = threadIdx.x;
    // preload all 128 words of this row, distributed across lanes
    unsigned long long nA = natW[b * 128 + lane],  nB = natW[b * 128 + 64 + lane];
    unsigned long long rA = realW[b * 128 + lane], rB = realW[b * 128 + 64 + lane];
    unsigned long long belowMask = lane ? (~0ULL >> (64 - lane)) : 0ULL;
    int carryNat = -1;
    int cnt = 0;
    for (int w = 0; w < 128; ++w) {
        unsigned long long nw = (w < 64) ? shfl64(nA, w) : shfl64(nB, w - 64);
        unsigned long long rw = (w < 64) ? shfl64(rA, w) : shfl64(rB, w - 64);
        int t = w * 64 + lane;
        unsigned long long nbelow = nw & belowMask;
        int p = nbelow ? (w * 64 + 63 - __clzll(nbelow)) : carryNat;
        bool natural = (nw >> lane) & 1;
        bool real    = (rw >> lane) & 1;
        bool fire = real && (natural || (((t - p) & 31) == 0));
        unsigned long long fb = __ballot(fire);
        if (fire) fires[b * TT + cnt + __popcll(fb & belowMask)] = t;
        cnt += (int)__popcll(fb);
        if (nw) carryNat = w * 64 + 63 - __clzll(nw);
    }
    if (lane == 0) nfires[b] = cnt;
}

// ---------------------------------------------------------------------------
// Kernel F: dense fill of all outputs (single write pass, no init needed).
// Thread g handles quad q=g&7 (slots 4q..4q+3) of phrase p=(g>>3)&8191,
// row b=g>>16.  Phrase p spans [fires[p-1]+1 , fires[p]] (len <= 32).
// Outputs are INT32 values (harness reads d_out as int32):
//   mask (0/1) | token_idx | end_pos, concatenated flat.
// ---------------------------------------------------------------------------
__global__ void fill_kernel(const int* __restrict__ fires,
                            const int* __restrict__ nfires,
                            int* __restrict__ out) {
    int g = blockIdx.x * blockDim.x + threadIdx.x;   // ((b*TT + p) * 8 + q)
    int q  = g & 7;
    int bp = g >> 3;                 // b*TT + p
    int b  = bp >> 13;
    int p  = bp & (TT - 1);
    int nf = nfires[b];
    int4 mv, tv;
    int endv;
    if (p < nf) {
        int end   = fires[b * TT + p];
        int start = (p > 0) ? (fires[b * TT + p - 1] + 1) : 0;
        int len   = end - start + 1;      // guaranteed 1..32
        int s0 = q * 4;
        int* mp = (int*)&mv;
        int* tp = (int*)&tv;
#pragma unroll
        for (int j = 0; j < 4; ++j) {
            int s = s0 + j;
            bool m = s < len;
            mp[j] = m ? 1 : 0;
            tp[j] = m ? (start + s) : 0;
        }
        endv = end;
    } else {
        mv = make_int4(0, 0, 0, 0);
        tv = mv;
        endv = -1;
    }
    const long long MOFF = (long long)BB * TT * 32;
    *(int4*)(out + (long long)bp * 32 + q * 4)        = mv;
    *(int4*)(out + MOFF + (long long)bp * 32 + q * 4) = tv;
    if (q == 0) out[2 * MOFF + bp] = endv;
}

extern "C" void kernel_launch(void* const* d_in, const int* in_sizes, int n_in,
                              void* d_out, int out_size, void* d_ws, size_t ws_size,
                              hipStream_t stream) {
    const int*  ids   = (const int*)d_in[0];
    const void* punct = d_in[1];
    const void* abbr  = d_in[2];
    char* ws = (char*)d_ws;
    int* flags   = (int*)(ws + WS_FLAGS);
    int* nfires  = (int*)(ws + WS_NFIRES);
    unsigned long long* natW  = (unsigned long long*)(ws + WS_NATW);
    unsigned long long* realW = (unsigned long long*)(ws + WS_REALW);
    int* fires   = (int*)(ws + WS_FIRES);
    int* out     = (int*)d_out;

    detect_kernel <<<1, 64, 0, stream>>>(punct, flags);
    natural_kernel<<<(BB * TT) / 256, 256, 0, stream>>>(ids, punct, abbr, flags, natW, realW);
    scan_kernel   <<<BB, 64, 0, stream>>>(natW, realW, fires, nfires);
    fill_kernel   <<<(BB * TT * 8) / 256, 256, 0, stream>>>(fires, nfires, out);
}

// Round 3
// 43.695 us; speedup vs baseline: 1.6149x; 1.6149x over previous
//
#include <hip/hip_runtime.h>
#include <stdint.h>

// Problem constants (fixed by setup_inputs)
#define BB 64
#define TT 8192
// max_phrase_len = 32, pad_token_id = 0 (hardcoded)

// Workspace layout (byte offsets)
#define WS_NFIRES  256                     // int[BB]
#define WS_FIRES   4096                    // int[BB*TT]

__device__ __forceinline__ unsigned long long bitsBelow(int e) {  // bits 0..e-1, e in [0,64]
    return (e >= 64) ? ~0ULL : ((1ULL << e) - 1ULL);
}

// ---------------------------------------------------------------------------
// prep_kernel: one block per row (1024 threads = 16 waves).
//  Phase 0: detect bool-table layout (0=int32, 1=uint8, 2=float32) from the
//           first 16KB of is_punct (in-bounds for all three layouts).
//  Phase 1: per-token natural-fire + real bits -> ballot-packed words in LDS.
//           natural[t] = real && ((punct[id] && !(t>0 && abbr[prev])) || t==last_real)
//           t==last_real is local (real prefix): real[t] && (t==T-1 || !real[t+1]).
//  Phase 2 (wave 0 only): WORD-PARALLEL fire scan.  Key identity:
//           fire[t] = real[t] && (natural[t] || t === prevNat(t)  (mod 32))
//           (forced fires occur exactly at prevNat + 32k; boundary init -1
//            behaves as position -1 => fires at t%32==31).
//           prevNat carry per word = exclusive MAX-scan of per-word last-nat
//           positions (identity -1).  Fire bits per word via segment walk over
//           its ~3 natural bits.  Compaction via exclusive ADD-scan of popcounts.
// ---------------------------------------------------------------------------
__global__ __launch_bounds__(1024) void prep_kernel(
        const int* __restrict__ ids,
        const void* __restrict__ punct,
        const void* __restrict__ abbr,
        int* __restrict__ fires, int* __restrict__ nfires) {
    __shared__ unsigned long long sNat[128], sReal[128];
    __shared__ int sFlag;
    int b = blockIdx.x;
    int tid = threadIdx.x;
    int wave = tid >> 6, lane = tid & 63;

    if (tid == 0) sFlag = 0;
    __syncthreads();
    {   // dtype probe: f32 words have bytes>1; uint8 packs set bits above byte0
        const uint32_t* w = (const uint32_t*)punct;
        bool byteGT1 = false, wordGT1 = false;
        for (int k = tid; k < 4096; k += 1024) {
            uint32_t x = w[k];
            byteGT1 |= (x & 0xFEFEFEFEu) != 0u;
            wordGT1 |= (x > 1u);
        }
        int local = (byteGT1 ? 2 : 0) | (wordGT1 ? 1 : 0);
        if (local) atomicOr(&sFlag, local);
    }
    __syncthreads();
    int fl = sFlag;
    int flag = (fl & 2) ? 2 : ((fl & 1) ? 1 : 0);

    const int* rowIds = ids + b * TT;
    for (int c = 0; c < 8; ++c) {
        int w = wave * 8 + c;            // word 0..127
        int t = w * 64 + lane;
        int id = rowIds[t];
        bool real = (id != 0);
        bool isLR = real && ((t == TT - 1) || (rowIds[t + 1] == 0));
        bool e = false;
        if (real) {
            bool pu, pa = false;
            if (flag == 2)      pu = ((const float*)punct)[id] != 0.0f;
            else if (flag == 1) pu = ((const uint8_t*)punct)[id] != 0;
            else                pu = ((const int*)punct)[id] != 0;
            if (t > 0) {
                int pid = rowIds[t - 1];
                if (flag == 2)      pa = ((const float*)abbr)[pid] != 0.0f;
                else if (flag == 1) pa = ((const uint8_t*)abbr)[pid] != 0;
                else                pa = ((const int*)abbr)[pid] != 0;
            }
            e = pu && !pa;
        }
        bool natural = real && (e || isLR);
        unsigned long long nb = __ballot(natural);
        unsigned long long rb = __ballot(real);
        if (lane == 0) { sNat[w] = nb; sReal[w] = rb; }
    }
    __syncthreads();

    if (wave != 0) return;
    // lane holds words {lane, lane+64}
    unsigned long long nA = sNat[lane],  nB = sNat[lane + 64];
    unsigned long long rA = sReal[lane], rB = sReal[lane + 64];
    int lnA = nA ? lane * 64 + 63 - __clzll(nA) : -1;
    int lnB = nB ? (lane + 64) * 64 + 63 - __clzll(nB) : -1;
    // exclusive max-scan for natural-position carries
    int sA = lnA;
    for (int d = 1; d < 64; d <<= 1) { int v = __shfl_up(sA, d); if (lane >= d) sA = max(sA, v); }
    int exA = __shfl_up(sA, 1); if (lane == 0) exA = -1;
    int totA = __shfl(sA, 63);
    int sB = lnB;
    for (int d = 1; d < 64; d <<= 1) { int v = __shfl_up(sB, d); if (lane >= d) sB = max(sB, v); }
    int exB = __shfl_up(sB, 1); if (lane == 0) exB = -1;
    exB = max(exB, totA);

    auto fireWord = [&](unsigned long long nw, unsigned long long rw,
                        int widx, int carry) -> unsigned long long {
        long long base = (long long)widx * 64;
        unsigned long long fire = 0, rem = nw;
        long long cur = carry;
        while (true) {
            int nxt = rem ? (__ffsll(rem) - 1) : 64;
            int r = (int)(((cur - base) % 32 + 32) % 32);
            unsigned long long pat = (1ULL << r) | (1ULL << (r + 32));
            int s = (int)(cur - base + 1); if (s < 0) s = 0;
            fire |= pat & bitsBelow(nxt) & ~bitsBelow(s);
            if (!rem) break;
            fire |= 1ULL << nxt;
            cur = base + nxt;
            rem &= rem - 1;
        }
        return fire & rw;
    };
    unsigned long long fA = fireWord(nA, rA, lane, exA);
    unsigned long long fB = fireWord(nB, rB, lane + 64, exB);
    // exclusive add-scan for compaction bases
    int pcA = __popcll(fA), pcB = __popcll(fB);
    int iA = pcA;
    for (int d = 1; d < 64; d <<= 1) { int v = __shfl_up(iA, d); if (lane >= d) iA += v; }
    int baseA = iA - pcA;
    int totPA = __shfl(iA, 63);
    int iB = pcB;
    for (int d = 1; d < 64; d <<= 1) { int v = __shfl_up(iB, d); if (lane >= d) iB += v; }
    int baseB = totPA + iB - pcB;
    int total = totPA + __shfl(iB, 63);
    // expand fire bits -> fire position list
    int* rowF = fires + b * TT;
    unsigned long long f = fA; int idx = baseA;
    while (f) { int t = __ffsll(f) - 1; rowF[idx++] = lane * 64 + t; f &= f - 1; }
    f = fB; idx = baseB;
    while (f) { int t = __ffsll(f) - 1; rowF[idx++] = (lane + 64) * 64 + t; f &= f - 1; }
    if (lane == 0) nfires[b] = total;
}

// ---------------------------------------------------------------------------
// fill_kernel: dense single-pass write of all outputs (int32 values).
// Thread g handles quad q=g&7 (slots 4q..4q+3) of phrase p=(g>>3)&8191, row
// b=g>>16.  Phrase p spans [fires[p-1]+1, fires[p]] (len 1..32 guaranteed).
// Outputs: mask(0/1) | token_idx | end_pos, concatenated flat.
// ---------------------------------------------------------------------------
__global__ void fill_kernel(const int* __restrict__ fires,
                            const int* __restrict__ nfires,
                            int* __restrict__ out) {
    int g = blockIdx.x * blockDim.x + threadIdx.x;   // ((b*TT + p) * 8 + q)
    int q  = g & 7;
    int bp = g >> 3;
    int b  = bp >> 13;
    int p  = bp & (TT - 1);
    int nf = nfires[b];
    int4 mv, tv;
    int endv;
    if (p < nf) {
        int end   = fires[b * TT + p];
        int start = (p > 0) ? (fires[b * TT + p - 1] + 1) : 0;
        int len   = end - start + 1;
        int s0 = q * 4;
        int* mp = (int*)&mv;
        int* tp = (int*)&tv;
#pragma unroll
        for (int j = 0; j < 4; ++j) {
            int s = s0 + j;
            bool m = s < len;
            mp[j] = m ? 1 : 0;
            tp[j] = m ? (start + s) : 0;
        }
        endv = end;
    } else {
        mv = make_int4(0, 0, 0, 0);
        tv = mv;
        endv = -1;
    }
    const long long MOFF = (long long)BB * TT * 32;
    *(int4*)(out + (long long)bp * 32 + q * 4)        = mv;
    *(int4*)(out + MOFF + (long long)bp * 32 + q * 4) = tv;
    if (q == 0) out[2 * MOFF + bp] = endv;
}

extern "C" void kernel_launch(void* const* d_in, const int* in_sizes, int n_in,
                              void* d_out, int out_size, void* d_ws, size_t ws_size,
                              hipStream_t stream) {
    const int*  ids   = (const int*)d_in[0];
    const void* punct = d_in[1];
    const void* abbr  = d_in[2];
    char* ws = (char*)d_ws;
    int* nfires = (int*)(ws + WS_NFIRES);
    int* fires  = (int*)(ws + WS_FIRES);
    int* out    = (int*)d_out;

    prep_kernel<<<BB, 1024, 0, stream>>>(ids, punct, abbr, fires, nfires);
    fill_kernel<<<(BB * TT * 8) / 256, 256, 0, stream>>>(fires, nfires, out);
}

// Round 4
// 34.309 us; speedup vs baseline: 2.0567x; 1.2736x over previous
//
#include <hip/hip_runtime.h>
#include <stdint.h>

// Problem constants (fixed by setup_inputs)
#define BB 64
#define TT 8192
// max_phrase_len = 32, pad_token_id = 0 (hardcoded)

// Workspace layout (byte offsets)
#define WS_NFIRES  256                     // int[BB]
#define WS_NATW    4096                    // uint64[BB*128]
#define WS_REALW   (4096 + 65536)          // uint64[BB*128]
#define WS_FIRES   (4096 + 2 * 65536)      // int[BB*TT]

__device__ __forceinline__ unsigned long long bitsBelow(int e) {  // bits 0..e-1, e in [0,64]
    return (e >= 64) ? ~0ULL : ((1ULL << e) - 1ULL);
}

__device__ __forceinline__ bool lut(const void* tbl, int flag, int idx) {
    if (flag == 2) return ((const float*)tbl)[idx]   != 0.0f;
    if (flag == 1) return ((const uint8_t*)tbl)[idx] != 0;
    return ((const int*)tbl)[idx] != 0;
}

// ---------------------------------------------------------------------------
// natural_kernel: full-grid (2048 blocks x 256) per-token natural/real bits.
//   natural[t] = real && ((punct[id] && !(t>0 && abbr[prev])) || t==last_real)
//   t==last_real is local (real prefix): real[t] && (t==T-1 || !real[t+1]).
// Per-block 4KB dtype probe (0=int32, 1=uint8, 2=float32); L2-broadcast, and
// at 5% punct density misdetection probability is ~5e-23.
// abbr gather predicated on punct hit (~5% of tokens) -> 95% fewer gathers.
// ---------------------------------------------------------------------------
__global__ __launch_bounds__(256) void natural_kernel(
        const int* __restrict__ ids,
        const void* __restrict__ punct,
        const void* __restrict__ abbr,
        unsigned long long* __restrict__ natW,
        unsigned long long* __restrict__ realW) {
    __shared__ int sFlag;
    if (threadIdx.x == 0) sFlag = 0;
    __syncthreads();
    {   // probe first 1024 int32 words (4KB; in-bounds for all 3 layouts)
        const uint32_t* w = (const uint32_t*)punct;
        bool byteGT1 = false, wordGT1 = false;
#pragma unroll
        for (int j = 0; j < 4; ++j) {
            uint32_t x = w[threadIdx.x * 4 + j];
            byteGT1 |= (x & 0xFEFEFEFEu) != 0u;   // f32: 1.0f has high bytes set
            wordGT1 |= (x > 1u);                  // uint8: packed bools > 1
        }
        int local = (byteGT1 ? 2 : 0) | (wordGT1 ? 1 : 0);
        if (local) atomicOr(&sFlag, local);
    }
    __syncthreads();
    int fl = sFlag;
    int flag = (fl & 2) ? 2 : (fl & 1);

    int g = blockIdx.x * 256 + threadIdx.x;   // g = b*TT + t
    int t = g & (TT - 1);
    int id = ids[g];
    bool real = (id != 0);
    bool isLR = real && ((t == TT - 1) || (ids[g + 1] == 0));
    bool e = false;
    if (real) {
        bool pu = lut(punct, flag, id);
        if (pu) {
            bool pa = (t > 0) ? lut(abbr, flag, ids[g - 1]) : false;
            e = !pa;
        }
    }
    bool natural = real && (e || isLR);
    unsigned long long nb = __ballot(natural);
    unsigned long long rb = __ballot(real);
    if ((threadIdx.x & 63) == 0) {
        int w = g >> 6;          // == b*128 + (t>>6)
        natW[w]  = nb;
        realW[w] = rb;
    }
}

// ---------------------------------------------------------------------------
// scan_kernel: one wave per row, WORD-PARALLEL fire scan.  Identity:
//   fire[t] = real[t] && (natural[t] || t === prevNat(t) (mod 32))
// (forced fires at prevNat+32k; init -1 behaves as position -1 => t%32==31).
// prevNat carry per word = exclusive MAX-scan (6 shfl steps) of per-word last
// natural positions; per-word fire bits via segment walk over its ~3 natural
// bits; compaction via exclusive ADD-scan of popcounts.
// ---------------------------------------------------------------------------
__global__ __launch_bounds__(64) void scan_kernel(
        const unsigned long long* __restrict__ natW,
        const unsigned long long* __restrict__ realW,
        int* __restrict__ fires, int* __restrict__ nfires) {
    int b = blockIdx.x, lane = threadIdx.x;
    unsigned long long nA = natW[b * 128 + lane],  nB = natW[b * 128 + 64 + lane];
    unsigned long long rA = realW[b * 128 + lane], rB = realW[b * 128 + 64 + lane];
    int lnA = nA ? lane * 64 + 63 - __clzll(nA) : -1;
    int lnB = nB ? (lane + 64) * 64 + 63 - __clzll(nB) : -1;
    // exclusive max-scan for natural-position carries
    int sA = lnA;
    for (int d = 1; d < 64; d <<= 1) { int v = __shfl_up(sA, d); if (lane >= d) sA = max(sA, v); }
    int exA = __shfl_up(sA, 1); if (lane == 0) exA = -1;
    int totA = __shfl(sA, 63);
    int sB = lnB;
    for (int d = 1; d < 64; d <<= 1) { int v = __shfl_up(sB, d); if (lane >= d) sB = max(sB, v); }
    int exB = __shfl_up(sB, 1); if (lane == 0) exB = -1;
    exB = max(exB, totA);

    auto fireWord = [&](unsigned long long nw, unsigned long long rw,
                        int widx, int carry) -> unsigned long long {
        long long base = (long long)widx * 64;
        unsigned long long fire = 0, rem = nw;
        long long cur = carry;
        while (true) {
            int nxt = rem ? (__ffsll(rem) - 1) : 64;
            int r = (int)(((cur - base) % 32 + 32) % 32);
            unsigned long long pat = (1ULL << r) | (1ULL << (r + 32));
            int s = (int)(cur - base + 1); if (s < 0) s = 0;
            fire |= pat & bitsBelow(nxt) & ~bitsBelow(s);
            if (!rem) break;
            fire |= 1ULL << nxt;
            cur = base + nxt;
            rem &= rem - 1;
        }
        return fire & rw;
    };
    unsigned long long fA = fireWord(nA, rA, lane, exA);
    unsigned long long fB = fireWord(nB, rB, lane + 64, exB);
    // exclusive add-scan for compaction bases
    int pcA = __popcll(fA), pcB = __popcll(fB);
    int iA = pcA;
    for (int d = 1; d < 64; d <<= 1) { int v = __shfl_up(iA, d); if (lane >= d) iA += v; }
    int baseA = iA - pcA;
    int totPA = __shfl(iA, 63);
    int iB = pcB;
    for (int d = 1; d < 64; d <<= 1) { int v = __shfl_up(iB, d); if (lane >= d) iB += v; }
    int baseB = totPA + iB - pcB;
    int total = totPA + __shfl(iB, 63);
    // expand fire bits -> fire position list
    int* rowF = fires + b * TT;
    unsigned long long f = fA; int idx = baseA;
    while (f) { int t = __ffsll(f) - 1; rowF[idx++] = lane * 64 + t; f &= f - 1; }
    f = fB; idx = baseB;
    while (f) { int t = __ffsll(f) - 1; rowF[idx++] = (lane + 64) * 64 + t; f &= f - 1; }
    if (lane == 0) nfires[b] = total;
}

// ---------------------------------------------------------------------------
// fill_kernel: dense single-pass write of all outputs (int32 values).
// Thread g handles quad q=g&7 (slots 4q..4q+3) of phrase p=(g>>3)&8191, row
// b=g>>16.  Phrase p spans [fires[p-1]+1, fires[p]] (len 1..32 guaranteed).
// Outputs: mask(0/1) | token_idx | end_pos, concatenated flat.
// ---------------------------------------------------------------------------
__global__ __launch_bounds__(256) void fill_kernel(
        const int* __restrict__ fires,
        const int* __restrict__ nfires,
        int* __restrict__ out) {
    int g = blockIdx.x * blockDim.x + threadIdx.x;   // ((b*TT + p) * 8 + q)
    int q  = g & 7;
    int bp = g >> 3;
    int b  = bp >> 13;
    int p  = bp & (TT - 1);
    int nf = nfires[b];
    int4 mv, tv;
    int endv;
    if (p < nf) {
        int end   = fires[b * TT + p];
        int start = (p > 0) ? (fires[b * TT + p - 1] + 1) : 0;
        int len   = end - start + 1;
        int s0 = q * 4;
        int* mp = (int*)&mv;
        int* tp = (int*)&tv;
#pragma unroll
        for (int j = 0; j < 4; ++j) {
            int s = s0 + j;
            bool m = s < len;
            mp[j] = m ? 1 : 0;
            tp[j] = m ? (start + s) : 0;
        }
        endv = end;
    } else {
        mv = make_int4(0, 0, 0, 0);
        tv = mv;
        endv = -1;
    }
    const long long MOFF = (long long)BB * TT * 32;
    *(int4*)(out + (long long)bp * 32 + q * 4)        = mv;
    *(int4*)(out + MOFF + (long long)bp * 32 + q * 4) = tv;
    if (q == 0) out[2 * MOFF + bp] = endv;
}

extern "C" void kernel_launch(void* const* d_in, const int* in_sizes, int n_in,
                              void* d_out, int out_size, void* d_ws, size_t ws_size,
                              hipStream_t stream) {
    const int*  ids   = (const int*)d_in[0];
    const void* punct = d_in[1];
    const void* abbr  = d_in[2];
    char* ws = (char*)d_ws;
    int* nfires = (int*)(ws + WS_NFIRES);
    unsigned long long* natW  = (unsigned long long*)(ws + WS_NATW);
    unsigned long long* realW = (unsigned long long*)(ws + WS_REALW);
    int* fires  = (int*)(ws + WS_FIRES);
    int* out    = (int*)d_out;

    natural_kernel<<<(BB * TT) / 256, 256, 0, stream>>>(ids, punct, abbr, natW, realW);
    scan_kernel   <<<BB, 64, 0, stream>>>(natW, realW, fires, nfires);
    fill_kernel   <<<(BB * TT * 8) / 256, 256, 0, stream>>>(fires, nfires, out);
}